// Round 1
// baseline (1078.135 us; speedup 1.0000x reference)
//
#include <hip/hip_runtime.h>
#include <math.h>

#define BB 8
#define NPTS 524288
#define G 128
#define GG (G*G)

// ws layout in floats
#define OFF_FIELD 0
#define OFF_COUNT (BB*4*GG)              // 524288
#define OFF_FAMAX (OFF_COUNT + BB*GG)    // 655360
#define OFF_T     (OFF_FAMAX + 8)        // 655368  (8B aligned in bytes)
#define OFF_Y     (OFF_T + BB*2*GG*2)    // 1179656

// ---------------- scatter: atomically accumulate 4 value channels + count ----
__global__ __launch_bounds__(256) void k_scatter(const float* __restrict__ yp,
                                                 const float* __restrict__ yt,
                                                 const float* __restrict__ co,
                                                 float* __restrict__ field,
                                                 float* __restrict__ cnt) {
    int i = blockIdx.x * 256 + threadIdx.x;     // point index over B*N
    int b = i >> 19;                            // / NPTS (2^19)
    float2 p = ((const float2*)yp)[i];
    float2 t = ((const float2*)yt)[i];
    size_t j = 3 * (size_t)i;
    float c0 = co[j], c1 = co[j + 1];
    // exactly mirror reference arithmetic: (c - min) / (max - min) * (G-1)
    float xn = (c0 - 0.0f) / 4.5f * 127.0f;
    float yn = (c1 - 0.5f) / 5.0f * 127.0f;
    int xi = (int)rintf(xn); xi = min(max(xi, 0), G - 1);
    int yi = (int)rintf(yn); yi = min(max(yi, 0), G - 1);
    int flat = yi * G + xi;
    float* fb = field + ((size_t)b * 4) * GG + flat;
    atomicAdd(fb, p.x);
    atomicAdd(fb + GG, p.y);
    atomicAdd(fb + 2 * GG, t.x);
    atomicAdd(fb + 3 * GG, t.y);
    atomicAdd(cnt + (size_t)b * GG + flat, 1.0f);
}

// ------------- divide by count + 3 hole-fill iterations, whole grid in LDS ---
// one block per (b, ch); 1024 threads; dynamic LDS = 2 * 16384 * 4 = 128 KiB
__global__ __launch_bounds__(1024) void k_holefill(float* __restrict__ field,
                                                   const float* __restrict__ cnt) {
    extern __shared__ float sm[];
    float* fs = sm;          // [G*G] field
    float* cs = sm + GG;     // [G*G] count
    int b = blockIdx.x >> 2, ch = blockIdx.x & 3;
    float* fg = field + ((size_t)b * 4 + ch) * GG;
    const float* cg = cnt + (size_t)b * GG;
    int tid = threadIdx.x;
    for (int k = 0; k < 16; k++) {
        int cell = tid + k * 1024;
        float c = cg[cell];
        float f = fg[cell];
        if (c > 0.f) f = f / c;
        fs[cell] = f;
        cs[cell] = c;
    }
    __syncthreads();
    float nf[16], nc[16];
    for (int it = 0; it < 3; ++it) {
        for (int k = 0; k < 16; k++) {
            int cell = tid + k * 1024;
            int y = cell >> 7, x = cell & 127;
            float c = cs[cell];
            float f = fs[cell];
            if (c == 0.f) {
                float s9 = 0.f;   // field: edge-replicate pad
                for (int dy = -1; dy <= 1; dy++)
                    for (int dx = -1; dx <= 1; dx++) {
                        int yy = min(max(y + dy, 0), G - 1);
                        int xx = min(max(x + dx, 0), G - 1);
                        s9 += fs[yy * G + xx];
                    }
                f = s9 * (1.0f / 9.0f);
                float c9 = 0.f;   // count: zero pad
                for (int dy = -1; dy <= 1; dy++)
                    for (int dx = -1; dx <= 1; dx++) {
                        int yy = y + dy, xx = x + dx;
                        if (yy >= 0 && yy < G && xx >= 0 && xx < G) c9 += cs[yy * G + xx];
                    }
                if (c9 > 0.f) c = 1.0f;
            }
            nf[k] = f; nc[k] = c;
        }
        __syncthreads();
        for (int k = 0; k < 16; k++) {
            int cell = tid + k * 1024;
            fs[cell] = nf[k];
            cs[cell] = nc[k];
        }
        __syncthreads();
    }
    for (int k = 0; k < 16; k++) {
        int cell = tid + k * 1024;
        fg[cell] = fs[cell];
    }
}

// ---------------- direct 128-pt DFT along rows, transposed output ------------
// PASS 0: in = field planar [B][4][G][G]; x[row][n] = ch(2f) + i*ch(2f+1)
// PASS 1: in = T interleaved complex [B][2][128][128]
// out[(b*2+f)*GG + k*128 + row] = sum_n x[row][n] * exp(-2*pi*i*k*n/128)
// (output permutation/transposition is irrelevant to the loss)
template <int PASS>
__global__ __launch_bounds__(256) void k_dft(const float* __restrict__ in,
                                             float* __restrict__ out,
                                             unsigned* __restrict__ famax) {
    __shared__ float2 xs[8][128];
    int blk = blockIdx.x;
    int rc = blk & 15;          // row-chunk: rows [rc*8, rc*8+8)
    int bf = blk >> 4;          // b*2 + f
    int tid = threadIdx.x;
    if (PASS == 0) {
        const float* re = in + ((size_t)(bf >> 1) * 4 + (size_t)(bf & 1) * 2) * GG + rc * 8 * G;
        const float* im = re + GG;
        for (int e = 0; e < 4; e++) {
            int idx = tid + e * 256;
            xs[idx >> 7][idx & 127] = make_float2(re[idx], im[idx]);
        }
    } else {
        const float2* cx = (const float2*)in + (size_t)bf * GG + rc * 8 * G;
        for (int e = 0; e < 4; e++) {
            int idx = tid + e * 256;
            xs[idx >> 7][idx & 127] = cx[idx];
        }
    }
    __syncthreads();

    int rloc = (tid >> 6) * 2;      // wave-uniform pair of rows
    int kk = tid & 63;              // k0 = kk, k1 = kk + 64
    float ang = -3.14159265358979323846f / 64.0f * (float)kk;
    float si, sr;
    sincosf(ang, &si, &sr);         // step = (sr, si) = e^{-2*pi*i*kk/128}

    float e0r = 0.f, e0i = 0.f, o0r = 0.f, o0i = 0.f;
    float e1r = 0.f, e1i = 0.f, o1r = 0.f, o1i = 0.f;
    float tr = 1.f, ti = 0.f;
#pragma unroll 8
    for (int n = 0; n < 128; n += 2) {
        float2 x0 = xs[rloc][n];
        float2 x1 = xs[rloc + 1][n];
        e0r += x0.x * tr - x0.y * ti;  e0i += x0.x * ti + x0.y * tr;
        e1r += x1.x * tr - x1.y * ti;  e1i += x1.x * ti + x1.y * tr;
        float t2r = tr * sr - ti * si, t2i = tr * si + ti * sr;
        x0 = xs[rloc][n + 1];
        x1 = xs[rloc + 1][n + 1];
        o0r += x0.x * t2r - x0.y * t2i;  o0i += x0.x * t2i + x0.y * t2r;
        o1r += x1.x * t2r - x1.y * t2i;  o1i += x1.x * t2i + x1.y * t2r;
        tr = t2r * sr - t2i * si;  ti = t2r * si + t2i * sr;
    }

    float2 a00 = make_float2(e0r + o0r, e0i + o0i);   // (k0, r0)
    float2 a01 = make_float2(e1r + o1r, e1i + o1i);   // (k0, r0+1)
    float2 a10 = make_float2(e0r - o0r, e0i - o0i);   // (k0+64, r0)
    float2 a11 = make_float2(e1r - o1r, e1i - o1i);   // (k0+64, r0+1)

    float2* ob = (float2*)out + (size_t)bf * GG;
    int r0 = rc * 8 + rloc;
    ob[kk * G + r0]            = a00;
    ob[kk * G + r0 + 1]        = a01;
    ob[(kk + 64) * G + r0]     = a10;
    ob[(kk + 64) * G + r0 + 1] = a11;

    if (PASS == 1 && (bf & 1)) {   // fft_true: track raw |Y| max per batch
        float m = fmaxf(fmaxf(sqrtf(a00.x * a00.x + a00.y * a00.y),
                              sqrtf(a01.x * a01.x + a01.y * a01.y)),
                        fmaxf(sqrtf(a10.x * a10.x + a10.y * a10.y),
                              sqrtf(a11.x * a11.x + a11.y * a11.y)));
        for (int off = 32; off; off >>= 1) m = fmaxf(m, __shfl_down(m, off));
        if ((tid & 63) == 0) atomicMax(&famax[bf >> 1], __float_as_uint(m));
    }
}

// ---------------- masked/weighted spectral loss, one block per batch ---------
__global__ __launch_bounds__(256) void k_loss(const float* __restrict__ Ybuf,
                                              const unsigned* __restrict__ famax,
                                              float* __restrict__ out) {
    int b = blockIdx.x;
    const float2* Yp = (const float2*)Ybuf + (size_t)(b * 2 + 0) * GG;
    const float2* Yt = (const float2*)Ybuf + (size_t)(b * 2 + 1) * GG;
    const float s = (4.5f / 127.0f) * (5.0f / 127.0f);   // dx*dy
    float fam = __uint_as_float(famax[b]) * s;
    float fam2 = fam * fam + 1e-10f;
    float thr = fam / 1000.0f;
    float swd = 0.f, smask = 0.f;
    for (int idx = threadIdx.x; idx < GG; idx += 256) {
        float2 p = Yp[idx], t = Yt[idx];
        float pr = p.x * s, pi = p.y * s;
        float qr = t.x * s, qi = t.y * s;
        float fa = sqrtf(qr * qr + qi * qi);
        if (fa >= thr) {
            float w = fa * fa / fam2;
            float dr = pr - qr, di = pi - qi;
            swd += (dr * dr + di * di) * w;
            smask += 1.f;
        }
    }
    for (int off = 32; off; off >>= 1) {
        swd += __shfl_down(swd, off);
        smask += __shfl_down(smask, off);
    }
    __shared__ float rs[4], rm[4];
    int wid = threadIdx.x >> 6, lane = threadIdx.x & 63;
    if (lane == 0) { rs[wid] = swd; rm[wid] = smask; }
    __syncthreads();
    if (threadIdx.x == 0) {
        float a = rs[0] + rs[1] + rs[2] + rs[3];
        float m = rm[0] + rm[1] + rm[2] + rm[3];
        atomicAdd(out, (a / (m + 1e-10f)) * 0.125f);
    }
}

extern "C" void kernel_launch(void* const* d_in, const int* in_sizes, int n_in,
                              void* d_out, int out_size, void* d_ws, size_t ws_size,
                              hipStream_t stream) {
    const float* yp = (const float*)d_in[0];
    const float* yt = (const float*)d_in[1];
    const float* co = (const float*)d_in[2];
    float* ws = (float*)d_ws;
    float* field = ws + OFF_FIELD;
    float* cnt   = ws + OFF_COUNT;
    unsigned* famax = (unsigned*)(ws + OFF_FAMAX);
    float* T = ws + OFF_T;
    float* Y = ws + OFF_Y;

    // zero accumulators (field + count + famax) and the scalar output
    hipMemsetAsync(d_ws, 0, (size_t)(OFF_FAMAX + 8) * sizeof(float), stream);
    hipMemsetAsync(d_out, 0, sizeof(float), stream);

    k_scatter<<<(BB * NPTS) / 256, 256, 0, stream>>>(yp, yt, co, field, cnt);
    k_holefill<<<BB * 4, 1024, 2 * GG * sizeof(float), stream>>>(field, cnt);
    k_dft<0><<<BB * 2 * 16, 256, 0, stream>>>(field, T, famax);
    k_dft<1><<<BB * 2 * 16, 256, 0, stream>>>(T, Y, famax);
    k_loss<<<BB, 256, 0, stream>>>(Y, famax, (float*)d_out);
}

// Round 2
// 200.529 us; speedup vs baseline: 5.3765x; 5.3765x over previous
//
#include <hip/hip_runtime.h>
#include <math.h>

#define BB 8
#define NPTS 524288
#define G 128
#define GG (G*G)
#define SLICES 4
#define CPS 4096          // cells per 32-row slice

// ws layout in floats
#define OFF_FIELD 0
#define OFF_COUNT (BB*4*GG)              // 524288
#define OFF_FAMAX (OFF_COUNT + BB*GG)    // 655360
#define OFF_T     (OFF_FAMAX + 8)        // 655368
#define OFF_Y     (OFF_T + BB*2*GG*2)    // 1179656
#define OFF_STAGE (OFF_T)                // stage aliases T/Y (dead before DFT)

// -------- scatter: LDS-private 5-plane accumulator per (batch, slice, rep) --
// dynamic LDS = 5*CPS*4 = 80 KiB; grid = BB*SLICES*rep blocks of 512 threads
__global__ __launch_bounds__(512) void k_scatter(const float* __restrict__ yp,
                                                 const float* __restrict__ yt,
                                                 const float* __restrict__ co,
                                                 float* __restrict__ stage,
                                                 int rep) {
    extern __shared__ float acc[];   // [5][CPS]
    int blk = blockIdx.x;            // ((b*SLICES + s)*rep + r)
    int r = blk % rep;
    int s = (blk / rep) % SLICES;
    int b = blk / (rep * SLICES);
    for (int k = threadIdx.x; k < 5 * CPS; k += 512) acc[k] = 0.f;
    __syncthreads();
    int ppb = NPTS / rep;
    size_t base = (size_t)b * NPTS + (size_t)r * ppb;
    for (int k = threadIdx.x; k < ppb; k += 512) {
        size_t i = base + k;
        float c0 = co[3 * i], c1 = co[3 * i + 1];
        // exactly mirror reference arithmetic (div then mul)
        float xn = (c0 - 0.0f) / 4.5f * 127.0f;
        float yn = (c1 - 0.5f) / 5.0f * 127.0f;
        int xi = min(max((int)rintf(xn), 0), G - 1);
        int yi = min(max((int)rintf(yn), 0), G - 1);
        if ((yi >> 5) != s) continue;            // not my slice
        int cell = (yi & 31) * G + xi;           // local cell in slice
        float2 p = ((const float2*)yp)[i];
        float2 t = ((const float2*)yt)[i];
        atomicAdd(&acc[cell], p.x);
        atomicAdd(&acc[CPS + cell], p.y);
        atomicAdd(&acc[2 * CPS + cell], t.x);
        atomicAdd(&acc[3 * CPS + cell], t.y);
        atomicAdd(&acc[4 * CPS + cell], 1.0f);
    }
    __syncthreads();
    float* sb = stage + (size_t)blk * (5 * CPS);
    for (int k = threadIdx.x; k < 5 * CPS; k += 512) sb[k] = acc[k];
}

// -------- reduce replicas + divide-by-count (plain writes, no atomics) ------
__global__ __launch_bounds__(256) void k_reduce(const float* __restrict__ stage,
                                                float* __restrict__ field,
                                                float* __restrict__ cnt,
                                                int rep) {
    int idx = blockIdx.x * 256 + threadIdx.x;    // over BB*SLICES*CPS = 131072
    int c = idx & (CPS - 1);
    int s = (idx >> 12) & 3;
    int b = idx >> 14;
    const float* sb = stage + ((size_t)(b * SLICES + s) * rep) * (5 * CPS) + c;
    float a0 = 0, a1 = 0, a2 = 0, a3 = 0, a4 = 0;
    for (int r = 0; r < rep; r++) {
        const float* p = sb + (size_t)r * 5 * CPS;
        a0 += p[0];
        a1 += p[CPS];
        a2 += p[2 * CPS];
        a3 += p[3 * CPS];
        a4 += p[4 * CPS];
    }
    if (a4 > 0.f) { a0 = a0 / a4; a1 = a1 / a4; a2 = a2 / a4; a3 = a3 / a4; }
    int flat = s * CPS + c;                      // global cell y*128+x
    size_t fb = ((size_t)b * 4) * GG + flat;
    field[fb]          = a0;
    field[fb + GG]     = a1;
    field[fb + 2 * GG] = a2;
    field[fb + 3 * GG] = a3;
    cnt[(size_t)b * GG + flat] = a4;
}

// -------- hole-fill (3 iters), early-exit when no empty cells (typical) -----
__global__ __launch_bounds__(1024) void k_holefill(float* __restrict__ field,
                                                   const float* __restrict__ cnt) {
    extern __shared__ float sm[];
    float* fs = sm;          // [G*G] field
    float* cs = sm + GG;     // [G*G] count
    __shared__ int anyhole;
    int b = blockIdx.x >> 2, ch = blockIdx.x & 3;
    float* fg = field + ((size_t)b * 4 + ch) * GG;
    const float* cg = cnt + (size_t)b * GG;
    int tid = threadIdx.x;
    if (tid == 0) anyhole = 0;
    __syncthreads();
    int myhole = 0;
    for (int k = 0; k < 16; k++) {
        int cell = tid + k * 1024;
        float c = cg[cell];
        cs[cell] = c;
        if (c == 0.f) myhole = 1;
    }
    if (__any(myhole)) { if ((tid & 63) == 0) anyhole = 1; }
    __syncthreads();
    if (!anyhole) return;            // no empty cells: field already final
    for (int k = 0; k < 16; k++) {
        int cell = tid + k * 1024;
        fs[cell] = fg[cell];
    }
    __syncthreads();
    float nf[16], nc[16];
    for (int it = 0; it < 3; ++it) {
        for (int k = 0; k < 16; k++) {
            int cell = tid + k * 1024;
            int y = cell >> 7, x = cell & 127;
            float c = cs[cell];
            float f = fs[cell];
            if (c == 0.f) {
                float s9 = 0.f;   // field: edge-replicate pad
                for (int dy = -1; dy <= 1; dy++)
                    for (int dx = -1; dx <= 1; dx++) {
                        int yy = min(max(y + dy, 0), G - 1);
                        int xx = min(max(x + dx, 0), G - 1);
                        s9 += fs[yy * G + xx];
                    }
                f = s9 * (1.0f / 9.0f);
                float c9 = 0.f;   // count: zero pad
                for (int dy = -1; dy <= 1; dy++)
                    for (int dx = -1; dx <= 1; dx++) {
                        int yy = y + dy, xx = x + dx;
                        if (yy >= 0 && yy < G && xx >= 0 && xx < G) c9 += cs[yy * G + xx];
                    }
                if (c9 > 0.f) c = 1.0f;
            }
            nf[k] = f; nc[k] = c;
        }
        __syncthreads();
        for (int k = 0; k < 16; k++) {
            int cell = tid + k * 1024;
            fs[cell] = nf[k];
            cs[cell] = nc[k];
        }
        __syncthreads();
    }
    for (int k = 0; k < 16; k++) {
        int cell = tid + k * 1024;
        fg[cell] = fs[cell];
    }
}

// ---------------- direct 128-pt DFT along rows, transposed output ------------
template <int PASS>
__global__ __launch_bounds__(256) void k_dft(const float* __restrict__ in,
                                             float* __restrict__ out,
                                             unsigned* __restrict__ famax) {
    __shared__ float2 xs[8][128];
    int blk = blockIdx.x;
    int rc = blk & 15;          // row-chunk: rows [rc*8, rc*8+8)
    int bf = blk >> 4;          // b*2 + f
    int tid = threadIdx.x;
    if (PASS == 0) {
        const float* re = in + ((size_t)(bf >> 1) * 4 + (size_t)(bf & 1) * 2) * GG + rc * 8 * G;
        const float* im = re + GG;
        for (int e = 0; e < 4; e++) {
            int idx = tid + e * 256;
            xs[idx >> 7][idx & 127] = make_float2(re[idx], im[idx]);
        }
    } else {
        const float2* cx = (const float2*)in + (size_t)bf * GG + rc * 8 * G;
        for (int e = 0; e < 4; e++) {
            int idx = tid + e * 256;
            xs[idx >> 7][idx & 127] = cx[idx];
        }
    }
    __syncthreads();

    int rloc = (tid >> 6) * 2;      // wave-uniform pair of rows
    int kk = tid & 63;              // k0 = kk, k1 = kk + 64
    float ang = -3.14159265358979323846f / 64.0f * (float)kk;
    float si, sr;
    sincosf(ang, &si, &sr);

    float e0r = 0.f, e0i = 0.f, o0r = 0.f, o0i = 0.f;
    float e1r = 0.f, e1i = 0.f, o1r = 0.f, o1i = 0.f;
    float tr = 1.f, ti = 0.f;
#pragma unroll 8
    for (int n = 0; n < 128; n += 2) {
        float2 x0 = xs[rloc][n];
        float2 x1 = xs[rloc + 1][n];
        e0r += x0.x * tr - x0.y * ti;  e0i += x0.x * ti + x0.y * tr;
        e1r += x1.x * tr - x1.y * ti;  e1i += x1.x * ti + x1.y * tr;
        float t2r = tr * sr - ti * si, t2i = tr * si + ti * sr;
        x0 = xs[rloc][n + 1];
        x1 = xs[rloc + 1][n + 1];
        o0r += x0.x * t2r - x0.y * t2i;  o0i += x0.x * t2i + x0.y * t2r;
        o1r += x1.x * t2r - x1.y * t2i;  o1i += x1.x * t2i + x1.y * t2r;
        tr = t2r * sr - t2i * si;  ti = t2r * si + t2i * sr;
    }

    float2 a00 = make_float2(e0r + o0r, e0i + o0i);
    float2 a01 = make_float2(e1r + o1r, e1i + o1i);
    float2 a10 = make_float2(e0r - o0r, e0i - o0i);
    float2 a11 = make_float2(e1r - o1r, e1i - o1i);

    float2* ob = (float2*)out + (size_t)bf * GG;
    int r0 = rc * 8 + rloc;
    ob[kk * G + r0]            = a00;
    ob[kk * G + r0 + 1]        = a01;
    ob[(kk + 64) * G + r0]     = a10;
    ob[(kk + 64) * G + r0 + 1] = a11;

    if (PASS == 1 && (bf & 1)) {   // fft_true: raw |Y| max per batch
        float m = fmaxf(fmaxf(sqrtf(a00.x * a00.x + a00.y * a00.y),
                              sqrtf(a01.x * a01.x + a01.y * a01.y)),
                        fmaxf(sqrtf(a10.x * a10.x + a10.y * a10.y),
                              sqrtf(a11.x * a11.x + a11.y * a11.y)));
        for (int off = 32; off; off >>= 1) m = fmaxf(m, __shfl_down(m, off));
        if ((tid & 63) == 0) atomicMax(&famax[bf >> 1], __float_as_uint(m));
    }
}

// ---------------- masked/weighted spectral loss, one block per batch ---------
__global__ __launch_bounds__(256) void k_loss(const float* __restrict__ Ybuf,
                                              const unsigned* __restrict__ famax,
                                              float* __restrict__ out) {
    int b = blockIdx.x;
    const float2* Yp = (const float2*)Ybuf + (size_t)(b * 2 + 0) * GG;
    const float2* Yt = (const float2*)Ybuf + (size_t)(b * 2 + 1) * GG;
    const float s = (4.5f / 127.0f) * (5.0f / 127.0f);   // dx*dy
    float fam = __uint_as_float(famax[b]) * s;
    float fam2 = fam * fam + 1e-10f;
    float thr = fam / 1000.0f;
    float swd = 0.f, smask = 0.f;
    for (int idx = threadIdx.x; idx < GG; idx += 256) {
        float2 p = Yp[idx], t = Yt[idx];
        float pr = p.x * s, pi = p.y * s;
        float qr = t.x * s, qi = t.y * s;
        float fa = sqrtf(qr * qr + qi * qi);
        if (fa >= thr) {
            float w = fa * fa / fam2;
            float dr = pr - qr, di = pi - qi;
            swd += (dr * dr + di * di) * w;
            smask += 1.f;
        }
    }
    for (int off = 32; off; off >>= 1) {
        swd += __shfl_down(swd, off);
        smask += __shfl_down(smask, off);
    }
    __shared__ float rs[4], rm[4];
    int wid = threadIdx.x >> 6, lane = threadIdx.x & 63;
    if (lane == 0) { rs[wid] = swd; rm[wid] = smask; }
    __syncthreads();
    if (threadIdx.x == 0) {
        float a = rs[0] + rs[1] + rs[2] + rs[3];
        float m = rm[0] + rm[1] + rm[2] + rm[3];
        atomicAdd(out, (a / (m + 1e-10f)) * 0.125f);
    }
}

extern "C" void kernel_launch(void* const* d_in, const int* in_sizes, int n_in,
                              void* d_out, int out_size, void* d_ws, size_t ws_size,
                              hipStream_t stream) {
    const float* yp = (const float*)d_in[0];
    const float* yt = (const float*)d_in[1];
    const float* co = (const float*)d_in[2];
    float* ws = (float*)d_ws;
    float* field = ws + OFF_FIELD;
    float* cnt   = ws + OFF_COUNT;
    unsigned* famax = (unsigned*)(ws + OFF_FAMAX);
    float* T = ws + OFF_T;
    float* Y = ws + OFF_Y;
    float* stage = ws + OFF_STAGE;

    // pick replication factor that fits ws (deterministic: ws_size is fixed)
    int rep = 8;
    while (rep > 1) {
        size_t need = ((size_t)OFF_T + (size_t)BB * SLICES * rep * 5 * CPS) * 4;
        size_t base = ((size_t)OFF_Y + (size_t)BB * 2 * GG * 2) * 4;
        if (need <= ws_size || need <= base) break;
        if (need <= ws_size) break;
        rep >>= 1;
    }

    // zero only famax + scalar output (field/cnt/stage fully overwritten)
    hipMemsetAsync((char*)d_ws + (size_t)OFF_FAMAX * 4, 0, 8 * sizeof(float), stream);
    hipMemsetAsync(d_out, 0, sizeof(float), stream);

    k_scatter<<<BB * SLICES * rep, 512, 5 * CPS * sizeof(float), stream>>>(yp, yt, co, stage, rep);
    k_reduce<<<BB * SLICES * CPS / 256, 256, 0, stream>>>(stage, field, cnt, rep);
    k_holefill<<<BB * 4, 1024, 2 * GG * sizeof(float), stream>>>(field, cnt);
    k_dft<0><<<BB * 2 * 16, 256, 0, stream>>>(field, T, famax);
    k_dft<1><<<BB * 2 * 16, 256, 0, stream>>>(T, Y, famax);
    k_loss<<<BB, 256, 0, stream>>>(Y, famax, (float*)d_out);
}

// Round 3
// 195.823 us; speedup vs baseline: 5.5057x; 1.0240x over previous
//
#include <hip/hip_runtime.h>
#include <math.h>

#define BB 8
#define NPTS 524288
#define G 128
#define GG (G*G)
#define SLICES 4
#define CPS 4096          // cells per 32-row slice

// ws layout in floats
#define OFF_FIELD 0
#define OFF_COUNT (BB*4*GG)              // 524288
#define OFF_FAMAX (OFF_COUNT + BB*GG)    // 655360
#define OFF_T     (OFF_FAMAX + 8)        // 655368
#define OFF_Y     (OFF_T + BB*2*GG*2)    // 1179656
#define OFF_STAGE (OFF_T)                // stage aliases T/Y (dead before DFT)

// -------- scatter: LDS-private 5-plane accumulator per (batch, slice, rep) --
// dynamic LDS = 5*CPS*4 = 80 KiB; 1024 threads; branchless, 4x-unrolled loads
__global__ __launch_bounds__(1024) void k_scatter(const float* __restrict__ yp,
                                                  const float* __restrict__ yt,
                                                  const float* __restrict__ co,
                                                  float* __restrict__ stage,
                                                  int rep) {
    extern __shared__ float acc[];   // [5][CPS]
    int blk = blockIdx.x;            // ((b*SLICES + s)*rep + r)
    int r = blk % rep;
    int s = (blk / rep) % SLICES;
    int b = blk / (rep * SLICES);
    for (int k = threadIdx.x; k < 5 * CPS; k += 1024) acc[k] = 0.f;
    __syncthreads();
    int ppb = NPTS / rep;            // multiple of 4096 for all rep in {1..16}
    size_t base = (size_t)b * NPTS + (size_t)r * ppb;
    const float2* ypp = (const float2*)yp;
    const float2* ytp = (const float2*)yt;
    for (int k = threadIdx.x; k < ppb; k += 4096) {
        float c0[4], c1[4];
        float2 p[4], t[4];
#pragma unroll
        for (int u = 0; u < 4; u++) {           // issue all 16 loads up front
            size_t i = base + k + u * 1024;
            c0[u] = co[3 * i];
            c1[u] = co[3 * i + 1];
            p[u] = ypp[i];
            t[u] = ytp[i];
        }
#pragma unroll
        for (int u = 0; u < 4; u++) {
            // exactly mirror reference arithmetic (div then mul)
            float xn = (c0[u] - 0.0f) / 4.5f * 127.0f;
            float yn = (c1[u] - 0.5f) / 5.0f * 127.0f;
            int xi = min(max((int)rintf(xn), 0), G - 1);
            int yi = min(max((int)rintf(yn), 0), G - 1);
            if ((yi >> 5) == s) {               // predicated LDS atomics only
                int cell = (yi & 31) * G + xi;
                atomicAdd(&acc[cell], p[u].x);
                atomicAdd(&acc[CPS + cell], p[u].y);
                atomicAdd(&acc[2 * CPS + cell], t[u].x);
                atomicAdd(&acc[3 * CPS + cell], t[u].y);
                atomicAdd(&acc[4 * CPS + cell], 1.0f);
            }
        }
    }
    __syncthreads();
    float* sb = stage + (size_t)blk * (5 * CPS);
    for (int k = threadIdx.x * 4; k < 5 * CPS; k += 4096)
        *(float4*)(sb + k) = *(const float4*)(acc + k);
}

// -------- reduce replicas + divide-by-count; also zeroes famax & out --------
__global__ __launch_bounds__(256) void k_reduce(const float* __restrict__ stage,
                                                float* __restrict__ field,
                                                float* __restrict__ cnt,
                                                unsigned* __restrict__ famax,
                                                float* __restrict__ out,
                                                int rep) {
    if (blockIdx.x == 0) {
        if (threadIdx.x < 8) famax[threadIdx.x] = 0u;
        if (threadIdx.x == 8) out[0] = 0.f;
    }
    int idx = blockIdx.x * 256 + threadIdx.x;    // over BB*SLICES*CPS = 131072
    int c = idx & (CPS - 1);
    int s = (idx >> 12) & 3;
    int b = idx >> 14;
    const float* sb = stage + ((size_t)(b * SLICES + s) * rep) * (5 * CPS) + c;
    float a0 = 0, a1 = 0, a2 = 0, a3 = 0, a4 = 0;
    for (int r = 0; r < rep; r++) {
        const float* p = sb + (size_t)r * 5 * CPS;
        a0 += p[0];
        a1 += p[CPS];
        a2 += p[2 * CPS];
        a3 += p[3 * CPS];
        a4 += p[4 * CPS];
    }
    if (a4 > 0.f) { a0 = a0 / a4; a1 = a1 / a4; a2 = a2 / a4; a3 = a3 / a4; }
    int flat = s * CPS + c;                      // global cell y*128+x
    size_t fb = ((size_t)b * 4) * GG + flat;
    field[fb]          = a0;
    field[fb + GG]     = a1;
    field[fb + 2 * GG] = a2;
    field[fb + 3 * GG] = a3;
    cnt[(size_t)b * GG + flat] = a4;
}

// -------- hole-fill (3 iters), early-exit when no empty cells (typical) -----
__global__ __launch_bounds__(1024) void k_holefill(float* __restrict__ field,
                                                   const float* __restrict__ cnt) {
    extern __shared__ float sm[];
    float* fs = sm;          // [G*G] field
    float* cs = sm + GG;     // [G*G] count
    __shared__ int anyhole;
    int b = blockIdx.x >> 2, ch = blockIdx.x & 3;
    float* fg = field + ((size_t)b * 4 + ch) * GG;
    const float* cg = cnt + (size_t)b * GG;
    int tid = threadIdx.x;
    if (tid == 0) anyhole = 0;
    __syncthreads();
    int myhole = 0;
    for (int k = 0; k < 16; k++) {
        int cell = tid + k * 1024;
        float c = cg[cell];
        cs[cell] = c;
        if (c == 0.f) myhole = 1;
    }
    if (__any(myhole)) { if ((tid & 63) == 0) anyhole = 1; }
    __syncthreads();
    if (!anyhole) return;            // no empty cells: field already final
    for (int k = 0; k < 16; k++) {
        int cell = tid + k * 1024;
        fs[cell] = fg[cell];
    }
    __syncthreads();
    float nf[16], nc[16];
    for (int it = 0; it < 3; ++it) {
        for (int k = 0; k < 16; k++) {
            int cell = tid + k * 1024;
            int y = cell >> 7, x = cell & 127;
            float c = cs[cell];
            float f = fs[cell];
            if (c == 0.f) {
                float s9 = 0.f;   // field: edge-replicate pad
                for (int dy = -1; dy <= 1; dy++)
                    for (int dx = -1; dx <= 1; dx++) {
                        int yy = min(max(y + dy, 0), G - 1);
                        int xx = min(max(x + dx, 0), G - 1);
                        s9 += fs[yy * G + xx];
                    }
                f = s9 * (1.0f / 9.0f);
                float c9 = 0.f;   // count: zero pad
                for (int dy = -1; dy <= 1; dy++)
                    for (int dx = -1; dx <= 1; dx++) {
                        int yy = y + dy, xx = x + dx;
                        if (yy >= 0 && yy < G && xx >= 0 && xx < G) c9 += cs[yy * G + xx];
                    }
                if (c9 > 0.f) c = 1.0f;
            }
            nf[k] = f; nc[k] = c;
        }
        __syncthreads();
        for (int k = 0; k < 16; k++) {
            int cell = tid + k * 1024;
            fs[cell] = nf[k];
            cs[cell] = nc[k];
        }
        __syncthreads();
    }
    for (int k = 0; k < 16; k++) {
        int cell = tid + k * 1024;
        fg[cell] = fs[cell];
    }
}

// ---------------- direct 128-pt DFT along rows, transposed output ------------
template <int PASS>
__global__ __launch_bounds__(256) void k_dft(const float* __restrict__ in,
                                             float* __restrict__ out,
                                             unsigned* __restrict__ famax) {
    __shared__ float2 xs[8][128];
    int blk = blockIdx.x;
    int rc = blk & 15;          // row-chunk: rows [rc*8, rc*8+8)
    int bf = blk >> 4;          // b*2 + f
    int tid = threadIdx.x;
    if (PASS == 0) {
        const float* re = in + ((size_t)(bf >> 1) * 4 + (size_t)(bf & 1) * 2) * GG + rc * 8 * G;
        const float* im = re + GG;
        for (int e = 0; e < 4; e++) {
            int idx = tid + e * 256;
            xs[idx >> 7][idx & 127] = make_float2(re[idx], im[idx]);
        }
    } else {
        const float2* cx = (const float2*)in + (size_t)bf * GG + rc * 8 * G;
        for (int e = 0; e < 4; e++) {
            int idx = tid + e * 256;
            xs[idx >> 7][idx & 127] = cx[idx];
        }
    }
    __syncthreads();

    int rloc = (tid >> 6) * 2;      // wave-uniform pair of rows
    int kk = tid & 63;              // k0 = kk, k1 = kk + 64
    float ang = -3.14159265358979323846f / 64.0f * (float)kk;
    float si, sr;
    sincosf(ang, &si, &sr);

    float e0r = 0.f, e0i = 0.f, o0r = 0.f, o0i = 0.f;
    float e1r = 0.f, e1i = 0.f, o1r = 0.f, o1i = 0.f;
    float tr = 1.f, ti = 0.f;
#pragma unroll 8
    for (int n = 0; n < 128; n += 2) {
        float2 x0 = xs[rloc][n];
        float2 x1 = xs[rloc + 1][n];
        e0r += x0.x * tr - x0.y * ti;  e0i += x0.x * ti + x0.y * tr;
        e1r += x1.x * tr - x1.y * ti;  e1i += x1.x * ti + x1.y * tr;
        float t2r = tr * sr - ti * si, t2i = tr * si + ti * sr;
        x0 = xs[rloc][n + 1];
        x1 = xs[rloc + 1][n + 1];
        o0r += x0.x * t2r - x0.y * t2i;  o0i += x0.x * t2i + x0.y * t2r;
        o1r += x1.x * t2r - x1.y * t2i;  o1i += x1.x * t2i + x1.y * t2r;
        tr = t2r * sr - t2i * si;  ti = t2r * si + t2i * sr;
    }

    float2 a00 = make_float2(e0r + o0r, e0i + o0i);
    float2 a01 = make_float2(e1r + o1r, e1i + o1i);
    float2 a10 = make_float2(e0r - o0r, e0i - o0i);
    float2 a11 = make_float2(e1r - o1r, e1i - o1i);

    float2* ob = (float2*)out + (size_t)bf * GG;
    int r0 = rc * 8 + rloc;
    ob[kk * G + r0]            = a00;
    ob[kk * G + r0 + 1]        = a01;
    ob[(kk + 64) * G + r0]     = a10;
    ob[(kk + 64) * G + r0 + 1] = a11;

    if (PASS == 1 && (bf & 1)) {   // fft_true: raw |Y| max per batch
        float m = fmaxf(fmaxf(sqrtf(a00.x * a00.x + a00.y * a00.y),
                              sqrtf(a01.x * a01.x + a01.y * a01.y)),
                        fmaxf(sqrtf(a10.x * a10.x + a10.y * a10.y),
                              sqrtf(a11.x * a11.x + a11.y * a11.y)));
        for (int off = 32; off; off >>= 1) m = fmaxf(m, __shfl_down(m, off));
        if ((tid & 63) == 0) atomicMax(&famax[bf >> 1], __float_as_uint(m));
    }
}

// ---------------- masked/weighted spectral loss, one block per batch ---------
__global__ __launch_bounds__(256) void k_loss(const float* __restrict__ Ybuf,
                                              const unsigned* __restrict__ famax,
                                              float* __restrict__ out) {
    int b = blockIdx.x;
    const float2* Yp = (const float2*)Ybuf + (size_t)(b * 2 + 0) * GG;
    const float2* Yt = (const float2*)Ybuf + (size_t)(b * 2 + 1) * GG;
    const float s = (4.5f / 127.0f) * (5.0f / 127.0f);   // dx*dy
    float fam = __uint_as_float(famax[b]) * s;
    float fam2 = fam * fam + 1e-10f;
    float thr = fam / 1000.0f;
    float swd = 0.f, smask = 0.f;
    for (int idx = threadIdx.x; idx < GG; idx += 256) {
        float2 p = Yp[idx], t = Yt[idx];
        float pr = p.x * s, pi = p.y * s;
        float qr = t.x * s, qi = t.y * s;
        float fa = sqrtf(qr * qr + qi * qi);
        if (fa >= thr) {
            float w = fa * fa / fam2;
            float dr = pr - qr, di = pi - qi;
            swd += (dr * dr + di * di) * w;
            smask += 1.f;
        }
    }
    for (int off = 32; off; off >>= 1) {
        swd += __shfl_down(swd, off);
        smask += __shfl_down(smask, off);
    }
    __shared__ float rs[4], rm[4];
    int wid = threadIdx.x >> 6, lane = threadIdx.x & 63;
    if (lane == 0) { rs[wid] = swd; rm[wid] = smask; }
    __syncthreads();
    if (threadIdx.x == 0) {
        float a = rs[0] + rs[1] + rs[2] + rs[3];
        float m = rm[0] + rm[1] + rm[2] + rm[3];
        atomicAdd(out, (a / (m + 1e-10f)) * 0.125f);
    }
}

extern "C" void kernel_launch(void* const* d_in, const int* in_sizes, int n_in,
                              void* d_out, int out_size, void* d_ws, size_t ws_size,
                              hipStream_t stream) {
    const float* yp = (const float*)d_in[0];
    const float* yt = (const float*)d_in[1];
    const float* co = (const float*)d_in[2];
    float* ws = (float*)d_ws;
    float* field = ws + OFF_FIELD;
    float* cnt   = ws + OFF_COUNT;
    unsigned* famax = (unsigned*)(ws + OFF_FAMAX);
    float* T = ws + OFF_T;
    float* Y = ws + OFF_Y;
    float* stage = ws + OFF_STAGE;

    // largest rep (power of 2, <=16) whose stage fits in ws; deterministic
    int rep = 16;
    while (rep > 1 &&
           ((size_t)OFF_T + (size_t)BB * SLICES * rep * 5 * CPS) * 4 > ws_size)
        rep >>= 1;

    k_scatter<<<BB * SLICES * rep, 1024, 5 * CPS * sizeof(float), stream>>>(yp, yt, co, stage, rep);
    k_reduce<<<BB * SLICES * CPS / 256, 256, 0, stream>>>(stage, field, cnt, famax, (float*)d_out, rep);
    k_holefill<<<BB * 4, 1024, 2 * GG * sizeof(float), stream>>>(field, cnt);
    k_dft<0><<<BB * 2 * 16, 256, 0, stream>>>(field, T, famax);
    k_dft<1><<<BB * 2 * 16, 256, 0, stream>>>(T, Y, famax);
    k_loss<<<BB, 256, 0, stream>>>(Y, famax, (float*)d_out);
}

// Round 4
// 178.427 us; speedup vs baseline: 6.0424x; 1.0975x over previous
//
#include <hip/hip_runtime.h>
#include <math.h>

#define BB 8
#define NPTS 524288
#define G 128
#define GG (G*G)
#define SLICES 2
#define CPS 8192          // cells per 64-row slice

// ws layout in floats
#define OFF_FIELD 0
#define OFF_COUNT (BB*4*GG)              // 524288
#define OFF_FAMAX (OFF_COUNT + BB*GG)    // 655360 (8 u32)
#define OFF_LSUM  (OFF_FAMAX + 8)        // 655368 (8 swd + 8 smask)
#define OFF_T     (OFF_FAMAX + 24)       // 655384 (16B aligned)
#define OFF_Y     (OFF_T + BB*2*GG*2)
#define OFF_STAGE (OFF_T)                // stage aliases T/Y (dead before DFT)

// -------- scatter: LDS-private 5-plane half-grid per (batch, slice, chunk) --
// dynamic LDS = 5*CPS*4 = 160 KiB (full CU pool, 1 block/CU, 16 waves)
// Each thread owns 4 consecutive points -> 7 independent float4 loads/quad,
// 2 quads unrolled = 14 wide loads in flight (defeats compiler load-sinking).
__global__ __launch_bounds__(1024) void k_scatter(const float4* __restrict__ co4,
                                                  const float4* __restrict__ yp4,
                                                  const float4* __restrict__ yt4,
                                                  float* __restrict__ stage,
                                                  int rep) {
    extern __shared__ float acc[];   // [5][CPS]
    int blk = blockIdx.x;            // ((b*SLICES + s)*rep + r)
    int r = blk % rep;
    int s = (blk / rep) % SLICES;
    int b = blk / (rep * SLICES);
    for (int k = threadIdx.x; k < 5 * CPS / 4; k += 1024)
        ((float4*)acc)[k] = make_float4(0.f, 0.f, 0.f, 0.f);
    __syncthreads();

    int ppb = NPTS / rep;
    int nq = ppb >> 2;                          // quads in this chunk (>=2048)
    size_t qbase = ((size_t)b * NPTS + (size_t)r * ppb) >> 2;

#define DOPT(cx, cy, vx, vy, wx, wy) do {                                  \
        float xn = ((cx) - 0.0f) / 4.5f * 127.0f;                          \
        float yn = ((cy) - 0.5f) / 5.0f * 127.0f;                          \
        int xi = min(max((int)rintf(xn), 0), G - 1);                       \
        int yi = min(max((int)rintf(yn), 0), G - 1);                       \
        if ((yi >> 6) == s) {                                              \
            int cell = (yi & 63) * G + xi;                                 \
            atomicAdd(&acc[cell], (vx));                                   \
            atomicAdd(&acc[CPS + cell], (vy));                             \
            atomicAdd(&acc[2 * CPS + cell], (wx));                         \
            atomicAdd(&acc[3 * CPS + cell], (wy));                         \
            atomicAdd(&acc[4 * CPS + cell], 1.0f);                        \
        }                                                                  \
    } while (0)

    for (int q = threadIdx.x; q < nq; q += 2048) {
        size_t qa = qbase + q, qb2 = qbase + q + 1024;
        // 14 independent wide loads, all issued before any use
        float4 A0 = co4[3 * qa], B0 = co4[3 * qa + 1], C0 = co4[3 * qa + 2];
        float4 P00 = yp4[2 * qa], P01 = yp4[2 * qa + 1];
        float4 T00 = yt4[2 * qa], T01 = yt4[2 * qa + 1];
        float4 A1 = co4[3 * qb2], B1 = co4[3 * qb2 + 1], C1 = co4[3 * qb2 + 2];
        float4 P10 = yp4[2 * qb2], P11 = yp4[2 * qb2 + 1];
        float4 T10 = yt4[2 * qb2], T11 = yt4[2 * qb2 + 1];

        DOPT(A0.x, A0.y, P00.x, P00.y, T00.x, T00.y);
        DOPT(A0.w, B0.x, P00.z, P00.w, T00.z, T00.w);
        DOPT(B0.z, B0.w, P01.x, P01.y, T01.x, T01.y);
        DOPT(C0.y, C0.z, P01.z, P01.w, T01.z, T01.w);

        DOPT(A1.x, A1.y, P10.x, P10.y, T10.x, T10.y);
        DOPT(A1.w, B1.x, P10.z, P10.w, T10.z, T10.w);
        DOPT(B1.z, B1.w, P11.x, P11.y, T11.x, T11.y);
        DOPT(C1.y, C1.z, P11.z, P11.w, T11.z, T11.w);
    }
#undef DOPT

    __syncthreads();
    float* sb = stage + (size_t)blk * (5 * CPS);
    for (int k = threadIdx.x * 4; k < 5 * CPS; k += 4096)
        *(float4*)(sb + k) = *(const float4*)(acc + k);
}

// -------- reduce replicas + divide-by-count; zeroes famax/loss-accum/out ----
__global__ __launch_bounds__(256) void k_reduce(const float* __restrict__ stage,
                                                float* __restrict__ field,
                                                float* __restrict__ cnt,
                                                unsigned* __restrict__ famax,
                                                float* __restrict__ lsum,
                                                float* __restrict__ out,
                                                int rep) {
    if (blockIdx.x == 0) {
        if (threadIdx.x < 8) famax[threadIdx.x] = 0u;
        if (threadIdx.x >= 8 && threadIdx.x < 24) lsum[threadIdx.x - 8] = 0.f;
        if (threadIdx.x == 24) out[0] = 0.f;
    }
    int idx = blockIdx.x * 256 + threadIdx.x;    // over BB*SLICES*CPS = 131072
    int c = idx & (CPS - 1);
    int s = (idx >> 13) & (SLICES - 1);
    int b = idx >> 14;
    const float* sb = stage + ((size_t)(b * SLICES + s) * rep) * (5 * CPS) + c;
    float a0 = 0, a1 = 0, a2 = 0, a3 = 0, a4 = 0;
    for (int r = 0; r < rep; r++) {
        const float* p = sb + (size_t)r * 5 * CPS;
        a0 += p[0];
        a1 += p[CPS];
        a2 += p[2 * CPS];
        a3 += p[3 * CPS];
        a4 += p[4 * CPS];
    }
    if (a4 > 0.f) { a0 = a0 / a4; a1 = a1 / a4; a2 = a2 / a4; a3 = a3 / a4; }
    int flat = s * CPS + c;                      // global cell y*128+x
    size_t fb = ((size_t)b * 4) * GG + flat;
    field[fb]          = a0;
    field[fb + GG]     = a1;
    field[fb + 2 * GG] = a2;
    field[fb + 3 * GG] = a3;
    cnt[(size_t)b * GG + flat] = a4;
}

// -------- hole-fill (3 iters), early-exit when no empty cells (typical) -----
__global__ __launch_bounds__(1024) void k_holefill(float* __restrict__ field,
                                                   const float* __restrict__ cnt) {
    extern __shared__ float sm[];
    float* fs = sm;          // [G*G] field
    float* cs = sm + GG;     // [G*G] count
    __shared__ int anyhole;
    int b = blockIdx.x >> 2, ch = blockIdx.x & 3;
    float* fg = field + ((size_t)b * 4 + ch) * GG;
    const float* cg = cnt + (size_t)b * GG;
    int tid = threadIdx.x;
    if (tid == 0) anyhole = 0;
    __syncthreads();
    int myhole = 0;
    for (int k = 0; k < 16; k++) {
        int cell = tid + k * 1024;
        float c = cg[cell];
        cs[cell] = c;
        if (c == 0.f) myhole = 1;
    }
    if (__any(myhole)) { if ((tid & 63) == 0) anyhole = 1; }
    __syncthreads();
    if (!anyhole) return;            // no empty cells: field already final
    for (int k = 0; k < 16; k++) {
        int cell = tid + k * 1024;
        fs[cell] = fg[cell];
    }
    __syncthreads();
    float nf[16], nc[16];
    for (int it = 0; it < 3; ++it) {
        for (int k = 0; k < 16; k++) {
            int cell = tid + k * 1024;
            int y = cell >> 7, x = cell & 127;
            float c = cs[cell];
            float f = fs[cell];
            if (c == 0.f) {
                float s9 = 0.f;   // field: edge-replicate pad
                for (int dy = -1; dy <= 1; dy++)
                    for (int dx = -1; dx <= 1; dx++) {
                        int yy = min(max(y + dy, 0), G - 1);
                        int xx = min(max(x + dx, 0), G - 1);
                        s9 += fs[yy * G + xx];
                    }
                f = s9 * (1.0f / 9.0f);
                float c9 = 0.f;   // count: zero pad
                for (int dy = -1; dy <= 1; dy++)
                    for (int dx = -1; dx <= 1; dx++) {
                        int yy = y + dy, xx = x + dx;
                        if (yy >= 0 && yy < G && xx >= 0 && xx < G) c9 += cs[yy * G + xx];
                    }
                if (c9 > 0.f) c = 1.0f;
            }
            nf[k] = f; nc[k] = c;
        }
        __syncthreads();
        for (int k = 0; k < 16; k++) {
            int cell = tid + k * 1024;
            fs[cell] = nf[k];
            cs[cell] = nc[k];
        }
        __syncthreads();
    }
    for (int k = 0; k < 16; k++) {
        int cell = tid + k * 1024;
        fg[cell] = fs[cell];
    }
}

// ---------------- direct 128-pt DFT along rows, transposed output ------------
template <int PASS>
__global__ __launch_bounds__(256) void k_dft(const float* __restrict__ in,
                                             float* __restrict__ out,
                                             unsigned* __restrict__ famax) {
    __shared__ float2 xs[8][128];
    int blk = blockIdx.x;
    int rc = blk & 15;          // row-chunk: rows [rc*8, rc*8+8)
    int bf = blk >> 4;          // b*2 + f
    int tid = threadIdx.x;
    if (PASS == 0) {
        const float* re = in + ((size_t)(bf >> 1) * 4 + (size_t)(bf & 1) * 2) * GG + rc * 8 * G;
        const float* im = re + GG;
        for (int e = 0; e < 4; e++) {
            int idx = tid + e * 256;
            xs[idx >> 7][idx & 127] = make_float2(re[idx], im[idx]);
        }
    } else {
        const float2* cx = (const float2*)in + (size_t)bf * GG + rc * 8 * G;
        for (int e = 0; e < 4; e++) {
            int idx = tid + e * 256;
            xs[idx >> 7][idx & 127] = cx[idx];
        }
    }
    __syncthreads();

    int rloc = (tid >> 6) * 2;      // wave-uniform pair of rows
    int kk = tid & 63;              // k0 = kk, k1 = kk + 64
    float ang = -3.14159265358979323846f / 64.0f * (float)kk;
    float si, sr;
    sincosf(ang, &si, &sr);

    float e0r = 0.f, e0i = 0.f, o0r = 0.f, o0i = 0.f;
    float e1r = 0.f, e1i = 0.f, o1r = 0.f, o1i = 0.f;
    float tr = 1.f, ti = 0.f;
#pragma unroll 8
    for (int n = 0; n < 128; n += 2) {
        float2 x0 = xs[rloc][n];
        float2 x1 = xs[rloc + 1][n];
        e0r += x0.x * tr - x0.y * ti;  e0i += x0.x * ti + x0.y * tr;
        e1r += x1.x * tr - x1.y * ti;  e1i += x1.x * ti + x1.y * tr;
        float t2r = tr * sr - ti * si, t2i = tr * si + ti * sr;
        x0 = xs[rloc][n + 1];
        x1 = xs[rloc + 1][n + 1];
        o0r += x0.x * t2r - x0.y * t2i;  o0i += x0.x * t2i + x0.y * t2r;
        o1r += x1.x * t2r - x1.y * t2i;  o1i += x1.x * t2i + x1.y * t2r;
        tr = t2r * sr - t2i * si;  ti = t2r * si + t2i * sr;
    }

    float2 a00 = make_float2(e0r + o0r, e0i + o0i);
    float2 a01 = make_float2(e1r + o1r, e1i + o1i);
    float2 a10 = make_float2(e0r - o0r, e0i - o0i);
    float2 a11 = make_float2(e1r - o1r, e1i - o1i);

    float2* ob = (float2*)out + (size_t)bf * GG;
    int r0 = rc * 8 + rloc;
    ob[kk * G + r0]            = a00;
    ob[kk * G + r0 + 1]        = a01;
    ob[(kk + 64) * G + r0]     = a10;
    ob[(kk + 64) * G + r0 + 1] = a11;

    if (PASS == 1 && (bf & 1)) {   // fft_true: raw |Y| max per batch
        float m = fmaxf(fmaxf(sqrtf(a00.x * a00.x + a00.y * a00.y),
                              sqrtf(a01.x * a01.x + a01.y * a01.y)),
                        fmaxf(sqrtf(a10.x * a10.x + a10.y * a10.y),
                              sqrtf(a11.x * a11.x + a11.y * a11.y)));
        for (int off = 32; off; off >>= 1) m = fmaxf(m, __shfl_down(m, off));
        if ((tid & 63) == 0) atomicMax(&famax[bf >> 1], __float_as_uint(m));
    }
}

// ------------- loss stage 1: 16 blocks/batch accumulate swd/smask -----------
__global__ __launch_bounds__(256) void k_loss1(const float* __restrict__ Ybuf,
                                               const unsigned* __restrict__ famax,
                                               float* __restrict__ lsum) {
    int b = blockIdx.x >> 4, seg = blockIdx.x & 15;
    const float2* Yp = (const float2*)Ybuf + (size_t)(b * 2 + 0) * GG;
    const float2* Yt = (const float2*)Ybuf + (size_t)(b * 2 + 1) * GG;
    const float s = (4.5f / 127.0f) * (5.0f / 127.0f);   // dx*dy
    float fam = __uint_as_float(famax[b]) * s;
    float fam2 = fam * fam + 1e-10f;
    float thr = fam / 1000.0f;
    float swd = 0.f, smask = 0.f;
    int base = seg * 1024;
    for (int k = 0; k < 4; k++) {
        int idx = base + threadIdx.x + k * 256;
        float2 p = Yp[idx], t = Yt[idx];
        float pr = p.x * s, pi = p.y * s;
        float qr = t.x * s, qi = t.y * s;
        float fa = sqrtf(qr * qr + qi * qi);
        if (fa >= thr) {
            float w = fa * fa / fam2;
            float dr = pr - qr, di = pi - qi;
            swd += (dr * dr + di * di) * w;
            smask += 1.f;
        }
    }
    for (int off = 32; off; off >>= 1) {
        swd += __shfl_down(swd, off);
        smask += __shfl_down(smask, off);
    }
    if ((threadIdx.x & 63) == 0) {
        atomicAdd(&lsum[b], swd);
        atomicAdd(&lsum[8 + b], smask);
    }
}

// ------------- loss stage 2: combine 8 batches -> scalar mean ---------------
__global__ __launch_bounds__(64) void k_loss2(const float* __restrict__ lsum,
                                              float* __restrict__ out) {
    int t = threadIdx.x;
    float v = 0.f;
    if (t < 8) v = lsum[t] / (lsum[8 + t] + 1e-10f);
    for (int off = 4; off; off >>= 1) v += __shfl_down(v, off);
    if (t == 0) out[0] = v * 0.125f;
}

extern "C" void kernel_launch(void* const* d_in, const int* in_sizes, int n_in,
                              void* d_out, int out_size, void* d_ws, size_t ws_size,
                              hipStream_t stream) {
    const float* yp = (const float*)d_in[0];
    const float* yt = (const float*)d_in[1];
    const float* co = (const float*)d_in[2];
    float* ws = (float*)d_ws;
    float* field = ws + OFF_FIELD;
    float* cnt   = ws + OFF_COUNT;
    unsigned* famax = (unsigned*)(ws + OFF_FAMAX);
    float* lsum  = ws + OFF_LSUM;
    float* T = ws + OFF_T;
    float* Y = ws + OFF_Y;
    float* stage = ws + OFF_STAGE;

    // largest rep (power of 2, <=32) whose stage fits in ws; deterministic
    int rep = 32;
    while (rep > 1 &&
           ((size_t)OFF_T + (size_t)BB * SLICES * rep * 5 * CPS) * 4 > ws_size)
        rep >>= 1;

    k_scatter<<<BB * SLICES * rep, 1024, 5 * CPS * sizeof(float), stream>>>(
        (const float4*)co, (const float4*)yp, (const float4*)yt, stage, rep);
    k_reduce<<<BB * SLICES * CPS / 256, 256, 0, stream>>>(stage, field, cnt, famax, lsum, (float*)d_out, rep);
    k_holefill<<<BB * 4, 1024, 2 * GG * sizeof(float), stream>>>(field, cnt);
    k_dft<0><<<BB * 2 * 16, 256, 0, stream>>>(field, T, famax);
    k_dft<1><<<BB * 2 * 16, 256, 0, stream>>>(T, Y, famax);
    k_loss1<<<BB * 16, 256, 0, stream>>>(Y, famax, lsum);
    k_loss2<<<1, 64, 0, stream>>>(lsum, (float*)d_out);
}

// Round 5
// 165.392 us; speedup vs baseline: 6.5187x; 1.0788x over previous
//
#include <hip/hip_runtime.h>
#include <math.h>

#define BB 8
#define NPTS 524288
#define G 128
#define GG (G*G)
#define SLICES 2
#define CPS 8192          // cells per 64-row slice

// ws layout in floats
#define OFF_FIELD 0
#define OFF_COUNT (BB*4*GG)              // 524288
#define OFF_FAMAX (OFF_COUNT + BB*GG)    // 655360 (8 u32)
#define OFF_LSUM  (OFF_FAMAX + 8)        // 655368 (8 swd + 8 smask)
#define OFF_T     (OFF_FAMAX + 24)       // 655384 (16B aligned)
#define OFF_Y     (OFF_T + BB*2*GG*2)
#define OFF_STAGE (OFF_T)                // stage aliases T/Y (dead before DFT)

// -------- scatter: LDS-private 5-plane half-grid, software-pipelined --------
// dynamic LDS = 5*CPS*4 = 160 KiB (1 block/CU, 16 waves); grid = 256 blocks.
// Register double-buffer: next iteration's 14 float4 loads issued before the
// current iteration's LDS atomics -> ~28 wide loads in flight per thread.
__global__ __launch_bounds__(1024) void k_scatter(const float4* __restrict__ co4,
                                                  const float4* __restrict__ yp4,
                                                  const float4* __restrict__ yt4,
                                                  float* __restrict__ stage,
                                                  int rep) {
    extern __shared__ float acc[];   // [5][CPS]
    int blk = blockIdx.x;            // ((b*SLICES + s)*rep + r)
    int r = blk % rep;
    int s = (blk / rep) % SLICES;
    int b = blk / (rep * SLICES);
    for (int k = threadIdx.x; k < 5 * CPS / 4; k += 1024)
        ((float4*)acc)[k] = make_float4(0.f, 0.f, 0.f, 0.f);
    __syncthreads();

    int ppb = NPTS / rep;
    int nq = ppb >> 2;                          // quads in this chunk
    int niter = nq >> 11;                       // pair-iterations (even for rep<=16)
    size_t qbase = ((size_t)b * NPTS + (size_t)r * ppb) >> 2;

#define DOPT(cx, cy, vx, vy, wx, wy) do {                                  \
        float xn = ((cx) - 0.0f) / 4.5f * 127.0f;                          \
        float yn = ((cy) - 0.5f) / 5.0f * 127.0f;                          \
        int xi = min(max((int)rintf(xn), 0), G - 1);                       \
        int yi = min(max((int)rintf(yn), 0), G - 1);                       \
        if ((yi >> 6) == s) {                                              \
            int cell = (yi & 63) * G + xi;                                 \
            atomicAdd(&acc[cell], (vx));                                   \
            atomicAdd(&acc[CPS + cell], (vy));                             \
            atomicAdd(&acc[2 * CPS + cell], (wx));                         \
            atomicAdd(&acc[3 * CPS + cell], (wy));                         \
            atomicAdd(&acc[4 * CPS + cell], 1.0f);                        \
        }                                                                  \
    } while (0)

#define DECLSET(S) float4 A##S, B##S, C##S, P0##S, P1##S, Q0##S, Q1##S,    \
                          D##S, E##S, F##S, P2##S, P3##S, Q2##S, Q3##S
#define LOADSET(S, it) do {                                                \
        size_t qa = qbase + threadIdx.x + (size_t)(it) * 2048;             \
        size_t qb = qa + 1024;                                             \
        A##S = co4[3 * qa]; B##S = co4[3 * qa + 1]; C##S = co4[3 * qa + 2];\
        P0##S = yp4[2 * qa]; P1##S = yp4[2 * qa + 1];                      \
        Q0##S = yt4[2 * qa]; Q1##S = yt4[2 * qa + 1];                      \
        D##S = co4[3 * qb]; E##S = co4[3 * qb + 1]; F##S = co4[3 * qb + 2];\
        P2##S = yp4[2 * qb]; P3##S = yp4[2 * qb + 1];                      \
        Q2##S = yt4[2 * qb]; Q3##S = yt4[2 * qb + 1];                      \
    } while (0)
#define PROCSET(S) do {                                                    \
        DOPT(A##S.x, A##S.y, P0##S.x, P0##S.y, Q0##S.x, Q0##S.y);          \
        DOPT(A##S.w, B##S.x, P0##S.z, P0##S.w, Q0##S.z, Q0##S.w);          \
        DOPT(B##S.z, B##S.w, P1##S.x, P1##S.y, Q1##S.x, Q1##S.y);          \
        DOPT(C##S.y, C##S.z, P1##S.z, P1##S.w, Q1##S.z, Q1##S.w);          \
        DOPT(D##S.x, D##S.y, P2##S.x, P2##S.y, Q2##S.x, Q2##S.y);          \
        DOPT(D##S.w, E##S.x, P2##S.z, P2##S.w, Q2##S.z, Q2##S.w);          \
        DOPT(E##S.z, E##S.w, P3##S.x, P3##S.y, Q3##S.x, Q3##S.y);          \
        DOPT(F##S.y, F##S.z, P3##S.z, P3##S.w, Q3##S.z, Q3##S.w);          \
    } while (0)

    DECLSET(X);
    DECLSET(Y);
    LOADSET(X, 0);
#pragma unroll 1
    for (int i = 0; i < niter; i += 2) {
        if (i + 1 < niter) LOADSET(Y, i + 1);   // prefetch (uniform branch)
        PROCSET(X);
        if (i + 2 < niter) LOADSET(X, i + 2);
        if (i + 1 < niter) PROCSET(Y);
    }
#undef DOPT
#undef DECLSET
#undef LOADSET
#undef PROCSET

    __syncthreads();
    float* sb = stage + (size_t)blk * (5 * CPS);
    for (int k = threadIdx.x * 4; k < 5 * CPS; k += 4096)
        *(float4*)(sb + k) = *(const float4*)(acc + k);
}

// -------- reduce replicas + divide-by-count (float4); zeroes famax/lsum/out -
// grid = BB*SLICES*CPS/4/256 = 128 blocks
__global__ __launch_bounds__(256) void k_reduce(const float4* __restrict__ stage4,
                                                float4* __restrict__ field4,
                                                float4* __restrict__ cnt4,
                                                unsigned* __restrict__ famax,
                                                float* __restrict__ lsum,
                                                float* __restrict__ out,
                                                int rep) {
    if (blockIdx.x == 0) {
        if (threadIdx.x < 8) famax[threadIdx.x] = 0u;
        if (threadIdx.x >= 8 && threadIdx.x < 24) lsum[threadIdx.x - 8] = 0.f;
        if (threadIdx.x == 24) out[0] = 0.f;
    }
    int idx = blockIdx.x * 256 + threadIdx.x;    // over BB*SLICES*(CPS/4)
    int c4 = idx & (CPS / 4 - 1);
    int s = (idx >> 11) & (SLICES - 1);
    int b = idx >> 12;
    const float4* sb = stage4 + ((size_t)(b * SLICES + s) * rep) * (5 * CPS / 4) + c4;
    float4 a0 = make_float4(0, 0, 0, 0), a1 = a0, a2 = a0, a3 = a0, a4 = a0;
    for (int r = 0; r < rep; r++) {
        const float4* p = sb + (size_t)r * (5 * CPS / 4);
        float4 v0 = p[0], v1 = p[CPS / 4], v2 = p[2 * (CPS / 4)];
        float4 v3 = p[3 * (CPS / 4)], v4 = p[4 * (CPS / 4)];
        a0.x += v0.x; a0.y += v0.y; a0.z += v0.z; a0.w += v0.w;
        a1.x += v1.x; a1.y += v1.y; a1.z += v1.z; a1.w += v1.w;
        a2.x += v2.x; a2.y += v2.y; a2.z += v2.z; a2.w += v2.w;
        a3.x += v3.x; a3.y += v3.y; a3.z += v3.z; a3.w += v3.w;
        a4.x += v4.x; a4.y += v4.y; a4.z += v4.z; a4.w += v4.w;
    }
#define DIV1(A, W) { if (a4.W > 0.f) { a0.W /= a4.W; a1.W /= a4.W; a2.W /= a4.W; a3.W /= a4.W; } }
    DIV1(a, x) DIV1(a, y) DIV1(a, z) DIV1(a, w)
#undef DIV1
    int flat4 = s * (CPS / 4) + c4;              // float4 index within grid
    size_t fb = ((size_t)b * 4) * (GG / 4) + flat4;
    field4[fb]              = a0;
    field4[fb + GG / 4]     = a1;
    field4[fb + 2 * (GG/4)] = a2;
    field4[fb + 3 * (GG/4)] = a3;
    cnt4[(size_t)b * (GG / 4) + flat4] = a4;
}

// -------- hole-fill (3 iters), early-exit when no empty cells (typical) -----
__global__ __launch_bounds__(1024) void k_holefill(float* __restrict__ field,
                                                   const float* __restrict__ cnt) {
    extern __shared__ float sm[];
    float* fs = sm;          // [G*G] field
    float* cs = sm + GG;     // [G*G] count
    __shared__ int anyhole;
    int b = blockIdx.x >> 2, ch = blockIdx.x & 3;
    float* fg = field + ((size_t)b * 4 + ch) * GG;
    const float* cg = cnt + (size_t)b * GG;
    int tid = threadIdx.x;
    if (tid == 0) anyhole = 0;
    __syncthreads();
    int myhole = 0;
    for (int k = 0; k < 16; k++) {
        int cell = tid + k * 1024;
        float c = cg[cell];
        cs[cell] = c;
        if (c == 0.f) myhole = 1;
    }
    if (__any(myhole)) { if ((tid & 63) == 0) anyhole = 1; }
    __syncthreads();
    if (!anyhole) return;            // no empty cells: field already final
    for (int k = 0; k < 16; k++) {
        int cell = tid + k * 1024;
        fs[cell] = fg[cell];
    }
    __syncthreads();
    float nf[16], nc[16];
    for (int it = 0; it < 3; ++it) {
        for (int k = 0; k < 16; k++) {
            int cell = tid + k * 1024;
            int y = cell >> 7, x = cell & 127;
            float c = cs[cell];
            float f = fs[cell];
            if (c == 0.f) {
                float s9 = 0.f;   // field: edge-replicate pad
                for (int dy = -1; dy <= 1; dy++)
                    for (int dx = -1; dx <= 1; dx++) {
                        int yy = min(max(y + dy, 0), G - 1);
                        int xx = min(max(x + dx, 0), G - 1);
                        s9 += fs[yy * G + xx];
                    }
                f = s9 * (1.0f / 9.0f);
                float c9 = 0.f;   // count: zero pad
                for (int dy = -1; dy <= 1; dy++)
                    for (int dx = -1; dx <= 1; dx++) {
                        int yy = y + dy, xx = x + dx;
                        if (yy >= 0 && yy < G && xx >= 0 && xx < G) c9 += cs[yy * G + xx];
                    }
                if (c9 > 0.f) c = 1.0f;
            }
            nf[k] = f; nc[k] = c;
        }
        __syncthreads();
        for (int k = 0; k < 16; k++) {
            int cell = tid + k * 1024;
            fs[cell] = nf[k];
            cs[cell] = nc[k];
        }
        __syncthreads();
    }
    for (int k = 0; k < 16; k++) {
        int cell = tid + k * 1024;
        fg[cell] = fs[cell];
    }
}

// ---------------- direct 128-pt DFT along rows, transposed output ------------
template <int PASS>
__global__ __launch_bounds__(256) void k_dft(const float* __restrict__ in,
                                             float* __restrict__ out,
                                             unsigned* __restrict__ famax) {
    __shared__ float2 xs[8][128];
    int blk = blockIdx.x;
    int rc = blk & 15;          // row-chunk: rows [rc*8, rc*8+8)
    int bf = blk >> 4;          // b*2 + f
    int tid = threadIdx.x;
    if (PASS == 0) {
        const float* re = in + ((size_t)(bf >> 1) * 4 + (size_t)(bf & 1) * 2) * GG + rc * 8 * G;
        const float* im = re + GG;
        for (int e = 0; e < 4; e++) {
            int idx = tid + e * 256;
            xs[idx >> 7][idx & 127] = make_float2(re[idx], im[idx]);
        }
    } else {
        const float2* cx = (const float2*)in + (size_t)bf * GG + rc * 8 * G;
        for (int e = 0; e < 4; e++) {
            int idx = tid + e * 256;
            xs[idx >> 7][idx & 127] = cx[idx];
        }
    }
    __syncthreads();

    int rloc = (tid >> 6) * 2;      // wave-uniform pair of rows
    int kk = tid & 63;              // k0 = kk, k1 = kk + 64
    float ang = -3.14159265358979323846f / 64.0f * (float)kk;
    float si, sr;
    sincosf(ang, &si, &sr);

    float e0r = 0.f, e0i = 0.f, o0r = 0.f, o0i = 0.f;
    float e1r = 0.f, e1i = 0.f, o1r = 0.f, o1i = 0.f;
    float tr = 1.f, ti = 0.f;
#pragma unroll 8
    for (int n = 0; n < 128; n += 2) {
        float2 x0 = xs[rloc][n];
        float2 x1 = xs[rloc + 1][n];
        e0r += x0.x * tr - x0.y * ti;  e0i += x0.x * ti + x0.y * tr;
        e1r += x1.x * tr - x1.y * ti;  e1i += x1.x * ti + x1.y * tr;
        float t2r = tr * sr - ti * si, t2i = tr * si + ti * sr;
        x0 = xs[rloc][n + 1];
        x1 = xs[rloc + 1][n + 1];
        o0r += x0.x * t2r - x0.y * t2i;  o0i += x0.x * t2i + x0.y * t2r;
        o1r += x1.x * t2r - x1.y * t2i;  o1i += x1.x * t2i + x1.y * t2r;
        tr = t2r * sr - t2i * si;  ti = t2r * si + t2i * sr;
    }

    float2 a00 = make_float2(e0r + o0r, e0i + o0i);
    float2 a01 = make_float2(e1r + o1r, e1i + o1i);
    float2 a10 = make_float2(e0r - o0r, e0i - o0i);
    float2 a11 = make_float2(e1r - o1r, e1i - o1i);

    float2* ob = (float2*)out + (size_t)bf * GG;
    int r0 = rc * 8 + rloc;
    ob[kk * G + r0]            = a00;
    ob[kk * G + r0 + 1]        = a01;
    ob[(kk + 64) * G + r0]     = a10;
    ob[(kk + 64) * G + r0 + 1] = a11;

    if (PASS == 1 && (bf & 1)) {   // fft_true: raw |Y| max per batch
        float m = fmaxf(fmaxf(sqrtf(a00.x * a00.x + a00.y * a00.y),
                              sqrtf(a01.x * a01.x + a01.y * a01.y)),
                        fmaxf(sqrtf(a10.x * a10.x + a10.y * a10.y),
                              sqrtf(a11.x * a11.x + a11.y * a11.y)));
        for (int off = 32; off; off >>= 1) m = fmaxf(m, __shfl_down(m, off));
        if ((tid & 63) == 0) atomicMax(&famax[bf >> 1], __float_as_uint(m));
    }
}

// ------------- loss stage 1: 16 blocks/batch accumulate swd/smask -----------
__global__ __launch_bounds__(256) void k_loss1(const float* __restrict__ Ybuf,
                                               const unsigned* __restrict__ famax,
                                               float* __restrict__ lsum) {
    int b = blockIdx.x >> 4, seg = blockIdx.x & 15;
    const float2* Yp = (const float2*)Ybuf + (size_t)(b * 2 + 0) * GG;
    const float2* Yt = (const float2*)Ybuf + (size_t)(b * 2 + 1) * GG;
    const float s = (4.5f / 127.0f) * (5.0f / 127.0f);   // dx*dy
    float fam = __uint_as_float(famax[b]) * s;
    float fam2 = fam * fam + 1e-10f;
    float thr = fam / 1000.0f;
    float swd = 0.f, smask = 0.f;
    int base = seg * 1024;
    for (int k = 0; k < 4; k++) {
        int idx = base + threadIdx.x + k * 256;
        float2 p = Yp[idx], t = Yt[idx];
        float pr = p.x * s, pi = p.y * s;
        float qr = t.x * s, qi = t.y * s;
        float fa = sqrtf(qr * qr + qi * qi);
        if (fa >= thr) {
            float w = fa * fa / fam2;
            float dr = pr - qr, di = pi - qi;
            swd += (dr * dr + di * di) * w;
            smask += 1.f;
        }
    }
    for (int off = 32; off; off >>= 1) {
        swd += __shfl_down(swd, off);
        smask += __shfl_down(smask, off);
    }
    if ((threadIdx.x & 63) == 0) {
        atomicAdd(&lsum[b], swd);
        atomicAdd(&lsum[8 + b], smask);
    }
}

// ------------- loss stage 2: combine 8 batches -> scalar mean ---------------
__global__ __launch_bounds__(64) void k_loss2(const float* __restrict__ lsum,
                                              float* __restrict__ out) {
    int t = threadIdx.x;
    float v = 0.f;
    if (t < 8) v = lsum[t] / (lsum[8 + t] + 1e-10f);
    for (int off = 4; off; off >>= 1) v += __shfl_down(v, off);
    if (t == 0) out[0] = v * 0.125f;
}

extern "C" void kernel_launch(void* const* d_in, const int* in_sizes, int n_in,
                              void* d_out, int out_size, void* d_ws, size_t ws_size,
                              hipStream_t stream) {
    const float* yp = (const float*)d_in[0];
    const float* yt = (const float*)d_in[1];
    const float* co = (const float*)d_in[2];
    float* ws = (float*)d_ws;
    float* field = ws + OFF_FIELD;
    float* cnt   = ws + OFF_COUNT;
    unsigned* famax = (unsigned*)(ws + OFF_FAMAX);
    float* lsum  = ws + OFF_LSUM;
    float* T = ws + OFF_T;
    float* Y = ws + OFF_Y;
    float* stage = ws + OFF_STAGE;

    // rep=16 -> grid 256 (1 block/CU); shrink only if ws can't hold the stage
    int rep = 16;
    while (rep > 1 &&
           ((size_t)OFF_T + (size_t)BB * SLICES * rep * 5 * CPS) * 4 > ws_size)
        rep >>= 1;

    k_scatter<<<BB * SLICES * rep, 1024, 5 * CPS * sizeof(float), stream>>>(
        (const float4*)co, (const float4*)yp, (const float4*)yt, stage, rep);
    k_reduce<<<BB * SLICES * (CPS / 4) / 256, 256, 0, stream>>>(
        (const float4*)stage, (float4*)field, (float4*)cnt, famax, lsum, (float*)d_out, rep);
    k_holefill<<<BB * 4, 1024, 2 * GG * sizeof(float), stream>>>(field, cnt);
    k_dft<0><<<BB * 2 * 16, 256, 0, stream>>>(field, T, famax);
    k_dft<1><<<BB * 2 * 16, 256, 0, stream>>>(T, Y, famax);
    k_loss1<<<BB * 16, 256, 0, stream>>>(Y, famax, lsum);
    k_loss2<<<1, 64, 0, stream>>>(lsum, (float*)d_out);
}

// Round 6
// 127.046 us; speedup vs baseline: 8.4862x; 1.3018x over previous
//
#include <hip/hip_runtime.h>
#include <hip/hip_fp16.h>
#include <math.h>

#define BB 8
#define NPTS 524288
#define G 128
#define GG (G*G)
#define SWORDS 40960      // u32 words per stage block: pv 16384 + tv 16384 + cn 8192

// ws layout in floats
#define OFF_FIELD 0
#define OFF_COUNT (BB*4*GG)              // 524288
#define OFF_FAMAX (OFF_COUNT + BB*GG)    // 655360 (8 u32)
#define OFF_LSUM  (OFF_FAMAX + 8)        // 655368 (8 swd + 8 smask)
#define OFF_T     (OFF_FAMAX + 24)       // 655384 (16B aligned: 655384*4 % 16 == 0)
#define OFF_Y     (OFF_T + BB*2*GG*2)
#define OFF_STAGE (OFF_T)                // stage aliases T/Y (dead before DFT)

__device__ __forceinline__ unsigned pack_h2(float x, float y) {
    __half2 h = __floats2half2_rn(x, y);
    return *(unsigned*)&h;
}

// -------- scatter: FULL grid per block, f16-packed planes, ds_pk_add_f16 ----
// LDS 160 KiB: [pv u32*16384][tv u32*16384][cn u32*8192]; 1 block/CU, 16 waves
// Each point read exactly once: 7 float4 loads / 4 points; 3 packed LDS
// atomics per point (no divergence, no slice filter).
__global__ __launch_bounds__(1024) void k_scatter(const float4* __restrict__ co4,
                                                  const float4* __restrict__ yp4,
                                                  const float4* __restrict__ yt4,
                                                  unsigned* __restrict__ stage,
                                                  int rep) {
    extern __shared__ unsigned sm[];   // [SWORDS]
    int blk = blockIdx.x;              // b*rep + r
    int r = blk % rep;
    int b = blk / rep;
    for (int k = threadIdx.x; k < SWORDS / 4; k += 1024)
        ((uint4*)sm)[k] = make_uint4(0u, 0u, 0u, 0u);
    __syncthreads();

    unsigned ldsbase = (unsigned)(uintptr_t)sm;   // LDS byte offset (aperture low bits)
    int ppb = NPTS / rep;
    int nq = ppb >> 2;                 // quads (multiple of 2048 for rep<=64)
    size_t qbase = ((size_t)b * NPTS + (size_t)r * ppb) >> 2;

#define DOPT(cx, cy, vx, vy, wx, wy) do {                                   \
        float xn = ((cx) - 0.0f) / 4.5f * 127.0f;                           \
        float yn = ((cy) - 0.5f) / 5.0f * 127.0f;                           \
        int xi = min(max((int)rintf(xn), 0), G - 1);                        \
        int yi = min(max((int)rintf(yn), 0), G - 1);                        \
        unsigned cell = (unsigned)(yi * G + xi);                            \
        unsigned av = ldsbase + cell * 4u;                                  \
        asm volatile("ds_pk_add_f16 %0, %1" :: "v"(av), "v"(pack_h2(vx, vy))); \
        asm volatile("ds_pk_add_f16 %0, %1" :: "v"(av + 65536u), "v"(pack_h2(wx, wy))); \
        unsigned ac = ldsbase + 131072u + (cell >> 1) * 4u;                 \
        unsigned cw = (cell & 1u) ? 0x3C000000u : 0x00003C00u;              \
        asm volatile("ds_pk_add_f16 %0, %1" :: "v"(ac), "v"(cw));           \
    } while (0)

    for (int q = threadIdx.x; q < nq; q += 2048) {
        size_t qa = qbase + q, qb = qa + 1024;
        // 14 independent float4 loads (two quads), issued before compute
        float4 A0 = co4[3 * qa], B0 = co4[3 * qa + 1], C0 = co4[3 * qa + 2];
        float4 P00 = yp4[2 * qa], P01 = yp4[2 * qa + 1];
        float4 Q00 = yt4[2 * qa], Q01 = yt4[2 * qa + 1];
        float4 A1 = co4[3 * qb], B1 = co4[3 * qb + 1], C1 = co4[3 * qb + 2];
        float4 P10 = yp4[2 * qb], P11 = yp4[2 * qb + 1];
        float4 Q10 = yt4[2 * qb], Q11 = yt4[2 * qb + 1];

        DOPT(A0.x, A0.y, P00.x, P00.y, Q00.x, Q00.y);
        DOPT(A0.w, B0.x, P00.z, P00.w, Q00.z, Q00.w);
        DOPT(B0.z, B0.w, P01.x, P01.y, Q01.x, Q01.y);
        DOPT(C0.y, C0.z, P01.z, P01.w, Q01.z, Q01.w);
        DOPT(A1.x, A1.y, P10.x, P10.y, Q10.x, Q10.y);
        DOPT(A1.w, B1.x, P10.z, P10.w, Q10.z, Q10.w);
        DOPT(B1.z, B1.w, P11.x, P11.y, Q11.x, Q11.y);
        DOPT(C1.y, C1.z, P11.z, P11.w, Q11.z, Q11.w);
    }
#undef DOPT

    // asm DS ops aren't compiler-tracked: drain before the barrier
    asm volatile("s_waitcnt lgkmcnt(0)" ::: "memory");
    __syncthreads();
    unsigned* sb = stage + (size_t)blk * SWORDS;
    for (int k = threadIdx.x * 4; k < SWORDS; k += 4096)
        *(uint4*)(sb + k) = *(const uint4*)(sm + k);
}

// -------- reduce replicas (f16->f32) + divide-by-count; zero famax/lsum/out -
// grid = BB*GG/2/256 = 256 blocks; thread handles cell pair (2k, 2k+1)
__global__ __launch_bounds__(256) void k_reduce(const unsigned* __restrict__ stage,
                                                float* __restrict__ field,
                                                float* __restrict__ cnt,
                                                unsigned* __restrict__ famax,
                                                float* __restrict__ lsum,
                                                float* __restrict__ out,
                                                int rep) {
    if (blockIdx.x == 0) {
        if (threadIdx.x < 8) famax[threadIdx.x] = 0u;
        if (threadIdx.x >= 8 && threadIdx.x < 24) lsum[threadIdx.x - 8] = 0.f;
        if (threadIdx.x == 24) out[0] = 0.f;
    }
    int idx = blockIdx.x * 256 + threadIdx.x;    // b*8192 + k
    int k = idx & 8191;
    int b = idx >> 13;
    const unsigned* sb = stage + (size_t)b * rep * SWORDS;
    float p0r = 0, p0i = 0, p1r = 0, p1i = 0;
    float t0r = 0, t0i = 0, t1r = 0, t1i = 0;
    float n0 = 0, n1 = 0;
    for (int r = 0; r < rep; r++) {
        const unsigned* pp = sb + (size_t)r * SWORDS;
        uint2 pv = *(const uint2*)(pp + 2 * k);
        uint2 tv = *(const uint2*)(pp + 16384 + 2 * k);
        unsigned cw = pp[32768 + k];
        float2 f;
        f = __half22float2(*(__half2*)&pv.x); p0r += f.x; p0i += f.y;
        f = __half22float2(*(__half2*)&pv.y); p1r += f.x; p1i += f.y;
        f = __half22float2(*(__half2*)&tv.x); t0r += f.x; t0i += f.y;
        f = __half22float2(*(__half2*)&tv.y); t1r += f.x; t1i += f.y;
        f = __half22float2(*(__half2*)&cw);   n0  += f.x; n1  += f.y;
    }
    if (n0 > 0.f) { p0r /= n0; p0i /= n0; t0r /= n0; t0i /= n0; }
    if (n1 > 0.f) { p1r /= n1; p1i /= n1; t1r /= n1; t1i /= n1; }
    float2* f2 = (float2*)field;
    size_t o = (size_t)b * 4 * (GG / 2) + k;
    f2[o]                = make_float2(p0r, p1r);
    f2[o + (GG / 2)]     = make_float2(p0i, p1i);
    f2[o + 2 * (GG / 2)] = make_float2(t0r, t1r);
    f2[o + 3 * (GG / 2)] = make_float2(t0i, t1i);
    ((float2*)cnt)[(size_t)b * (GG / 2) + k] = make_float2(n0, n1);
}

// -------- hole-fill (3 iters), early-exit when no empty cells (typical) -----
__global__ __launch_bounds__(1024) void k_holefill(float* __restrict__ field,
                                                   const float* __restrict__ cnt) {
    extern __shared__ float smf[];
    float* fs = smf;         // [G*G] field
    float* cs = smf + GG;    // [G*G] count
    __shared__ int anyhole;
    int b = blockIdx.x >> 2, ch = blockIdx.x & 3;
    float* fg = field + ((size_t)b * 4 + ch) * GG;
    const float* cg = cnt + (size_t)b * GG;
    int tid = threadIdx.x;
    if (tid == 0) anyhole = 0;
    __syncthreads();
    int myhole = 0;
    for (int k = 0; k < 16; k++) {
        int cell = tid + k * 1024;
        float c = cg[cell];
        cs[cell] = c;
        if (c == 0.f) myhole = 1;
    }
    if (__any(myhole)) { if ((tid & 63) == 0) anyhole = 1; }
    __syncthreads();
    if (!anyhole) return;            // no empty cells: field already final
    for (int k = 0; k < 16; k++) {
        int cell = tid + k * 1024;
        fs[cell] = fg[cell];
    }
    __syncthreads();
    float nf[16], nc[16];
    for (int it = 0; it < 3; ++it) {
        for (int k = 0; k < 16; k++) {
            int cell = tid + k * 1024;
            int y = cell >> 7, x = cell & 127;
            float c = cs[cell];
            float f = fs[cell];
            if (c == 0.f) {
                float s9 = 0.f;   // field: edge-replicate pad
                for (int dy = -1; dy <= 1; dy++)
                    for (int dx = -1; dx <= 1; dx++) {
                        int yy = min(max(y + dy, 0), G - 1);
                        int xx = min(max(x + dx, 0), G - 1);
                        s9 += fs[yy * G + xx];
                    }
                f = s9 * (1.0f / 9.0f);
                float c9 = 0.f;   // count: zero pad
                for (int dy = -1; dy <= 1; dy++)
                    for (int dx = -1; dx <= 1; dx++) {
                        int yy = y + dy, xx = x + dx;
                        if (yy >= 0 && yy < G && xx >= 0 && xx < G) c9 += cs[yy * G + xx];
                    }
                if (c9 > 0.f) c = 1.0f;
            }
            nf[k] = f; nc[k] = c;
        }
        __syncthreads();
        for (int k = 0; k < 16; k++) {
            int cell = tid + k * 1024;
            fs[cell] = nf[k];
            cs[cell] = nc[k];
        }
        __syncthreads();
    }
    for (int k = 0; k < 16; k++) {
        int cell = tid + k * 1024;
        fg[cell] = fs[cell];
    }
}

// ---------------- direct 128-pt DFT along rows, transposed output ------------
template <int PASS>
__global__ __launch_bounds__(256) void k_dft(const float* __restrict__ in,
                                             float* __restrict__ out,
                                             unsigned* __restrict__ famax) {
    __shared__ float2 xs[8][128];
    int blk = blockIdx.x;
    int rc = blk & 15;          // row-chunk: rows [rc*8, rc*8+8)
    int bf = blk >> 4;          // b*2 + f
    int tid = threadIdx.x;
    if (PASS == 0) {
        const float* re = in + ((size_t)(bf >> 1) * 4 + (size_t)(bf & 1) * 2) * GG + rc * 8 * G;
        const float* im = re + GG;
        for (int e = 0; e < 4; e++) {
            int idx = tid + e * 256;
            xs[idx >> 7][idx & 127] = make_float2(re[idx], im[idx]);
        }
    } else {
        const float2* cx = (const float2*)in + (size_t)bf * GG + rc * 8 * G;
        for (int e = 0; e < 4; e++) {
            int idx = tid + e * 256;
            xs[idx >> 7][idx & 127] = cx[idx];
        }
    }
    __syncthreads();

    int rloc = (tid >> 6) * 2;      // wave-uniform pair of rows
    int kk = tid & 63;              // k0 = kk, k1 = kk + 64
    float ang = -3.14159265358979323846f / 64.0f * (float)kk;
    float si, sr;
    sincosf(ang, &si, &sr);

    float e0r = 0.f, e0i = 0.f, o0r = 0.f, o0i = 0.f;
    float e1r = 0.f, e1i = 0.f, o1r = 0.f, o1i = 0.f;
    float tr = 1.f, ti = 0.f;
#pragma unroll 8
    for (int n = 0; n < 128; n += 2) {
        float2 x0 = xs[rloc][n];
        float2 x1 = xs[rloc + 1][n];
        e0r += x0.x * tr - x0.y * ti;  e0i += x0.x * ti + x0.y * tr;
        e1r += x1.x * tr - x1.y * ti;  e1i += x1.x * ti + x1.y * tr;
        float t2r = tr * sr - ti * si, t2i = tr * si + ti * sr;
        x0 = xs[rloc][n + 1];
        x1 = xs[rloc + 1][n + 1];
        o0r += x0.x * t2r - x0.y * t2i;  o0i += x0.x * t2i + x0.y * t2r;
        o1r += x1.x * t2r - x1.y * t2i;  o1i += x1.x * t2i + x1.y * t2r;
        tr = t2r * sr - t2i * si;  ti = t2r * si + t2i * sr;
    }

    float2 a00 = make_float2(e0r + o0r, e0i + o0i);
    float2 a01 = make_float2(e1r + o1r, e1i + o1i);
    float2 a10 = make_float2(e0r - o0r, e0i - o0i);
    float2 a11 = make_float2(e1r - o1r, e1i - o1i);

    float2* ob = (float2*)out + (size_t)bf * GG;
    int r0 = rc * 8 + rloc;
    ob[kk * G + r0]            = a00;
    ob[kk * G + r0 + 1]        = a01;
    ob[(kk + 64) * G + r0]     = a10;
    ob[(kk + 64) * G + r0 + 1] = a11;

    if (PASS == 1 && (bf & 1)) {   // fft_true: raw |Y| max per batch
        float m = fmaxf(fmaxf(sqrtf(a00.x * a00.x + a00.y * a00.y),
                              sqrtf(a01.x * a01.x + a01.y * a01.y)),
                        fmaxf(sqrtf(a10.x * a10.x + a10.y * a10.y),
                              sqrtf(a11.x * a11.x + a11.y * a11.y)));
        for (int off = 32; off; off >>= 1) m = fmaxf(m, __shfl_down(m, off));
        if ((tid & 63) == 0) atomicMax(&famax[bf >> 1], __float_as_uint(m));
    }
}

// ------------- loss stage 1: 16 blocks/batch accumulate swd/smask -----------
__global__ __launch_bounds__(256) void k_loss1(const float* __restrict__ Ybuf,
                                               const unsigned* __restrict__ famax,
                                               float* __restrict__ lsum) {
    int b = blockIdx.x >> 4, seg = blockIdx.x & 15;
    const float2* Yp = (const float2*)Ybuf + (size_t)(b * 2 + 0) * GG;
    const float2* Yt = (const float2*)Ybuf + (size_t)(b * 2 + 1) * GG;
    const float s = (4.5f / 127.0f) * (5.0f / 127.0f);   // dx*dy
    float fam = __uint_as_float(famax[b]) * s;
    float fam2 = fam * fam + 1e-10f;
    float thr = fam / 1000.0f;
    float swd = 0.f, smask = 0.f;
    int base = seg * 1024;
    for (int k = 0; k < 4; k++) {
        int idx = base + threadIdx.x + k * 256;
        float2 p = Yp[idx], t = Yt[idx];
        float pr = p.x * s, pi = p.y * s;
        float qr = t.x * s, qi = t.y * s;
        float fa = sqrtf(qr * qr + qi * qi);
        if (fa >= thr) {
            float w = fa * fa / fam2;
            float dr = pr - qr, di = pi - qi;
            swd += (dr * dr + di * di) * w;
            smask += 1.f;
        }
    }
    for (int off = 32; off; off >>= 1) {
        swd += __shfl_down(swd, off);
        smask += __shfl_down(smask, off);
    }
    if ((threadIdx.x & 63) == 0) {
        atomicAdd(&lsum[b], swd);
        atomicAdd(&lsum[8 + b], smask);
    }
}

// ------------- loss stage 2: combine 8 batches -> scalar mean ---------------
__global__ __launch_bounds__(64) void k_loss2(const float* __restrict__ lsum,
                                              float* __restrict__ out) {
    int t = threadIdx.x;
    float v = 0.f;
    if (t < 8) v = lsum[t] / (lsum[8 + t] + 1e-10f);
    for (int off = 4; off; off >>= 1) v += __shfl_down(v, off);
    if (t == 0) out[0] = v * 0.125f;
}

extern "C" void kernel_launch(void* const* d_in, const int* in_sizes, int n_in,
                              void* d_out, int out_size, void* d_ws, size_t ws_size,
                              hipStream_t stream) {
    const float* yp = (const float*)d_in[0];
    const float* yt = (const float*)d_in[1];
    const float* co = (const float*)d_in[2];
    float* ws = (float*)d_ws;
    float* field = ws + OFF_FIELD;
    float* cnt   = ws + OFF_COUNT;
    unsigned* famax = (unsigned*)(ws + OFF_FAMAX);
    float* lsum  = ws + OFF_LSUM;
    float* T = ws + OFF_T;
    float* Y = ws + OFF_Y;
    unsigned* stage = (unsigned*)(ws + OFF_STAGE);

    // rep=32 -> grid 256 (1 block/CU); shrink only if ws can't hold the stage
    int rep = 32;
    while (rep > 1 &&
           ((size_t)OFF_T + (size_t)BB * rep * SWORDS) * 4 > ws_size)
        rep >>= 1;

    k_scatter<<<BB * rep, 1024, SWORDS * sizeof(unsigned), stream>>>(
        (const float4*)co, (const float4*)yp, (const float4*)yt, stage, rep);
    k_reduce<<<BB * (GG / 2) / 256, 256, 0, stream>>>(
        stage, field, cnt, famax, lsum, (float*)d_out, rep);
    k_holefill<<<BB * 4, 1024, 2 * GG * sizeof(float), stream>>>(field, cnt);
    k_dft<0><<<BB * 2 * 16, 256, 0, stream>>>(field, T, famax);
    k_dft<1><<<BB * 2 * 16, 256, 0, stream>>>(T, Y, famax);
    k_loss1<<<BB * 16, 256, 0, stream>>>(Y, famax, lsum);
    k_loss2<<<1, 64, 0, stream>>>(lsum, (float*)d_out);
}